// Round 16
// baseline (132.303 us; speedup 1.0000x reference)
//
#include <hip/hip_runtime.h>
#include <hip/hip_bf16.h>
#include <stdint.h>

#define B_ 2
#define S_ 2048
#define H_ 32
#define D_ 128
#define R_ (B_*H_*S_)           // 131072 (b,h,s) rows
#define PG 2048                 // prep grid size
#define CPB 40                  // uniform k-chunks (<=8 64-row tiles) per bh

typedef __bf16 bf16x8 __attribute__((ext_vector_type(8)));
typedef float  f32x16 __attribute__((ext_vector_type(16)));
typedef float  f32x4v __attribute__((ext_vector_type(4)));
typedef unsigned short u16x4 __attribute__((ext_vector_type(4)));

#if __has_builtin(__builtin_amdgcn_exp2f)
#define EXP2F(x) __builtin_amdgcn_exp2f(x)
#else
#define EXP2F(x) exp2f(x)
#endif

#define AS1 __attribute__((address_space(1)))
#define AS3 __attribute__((address_space(3)))

__device__ __forceinline__ unsigned short f2bf(float f) {
  unsigned u = __float_as_uint(f);
  u += 0x7FFFu + ((u >> 16) & 1u);
  return (unsigned short)(u >> 16);
}

// Prep: pure streaming convert with NON-TEMPORAL input loads. q,k,v are each
// read exactly ONCE per replay, so they must not evict the L3-resident
// qc/kc that attn re-reads -- R15's cached input stream pushed the working
// set to ~258MB (== L3) and thrashed (prep 84us @ 2.1 TB/s). Lane-contiguous
// float4 reads (1KB/instr) and ushort4 stores (512B/instr), textbook G2/G13.
__global__ __launch_bounds__(256) void prep(
    const float* __restrict__ qf, const float* __restrict__ kf,
    const float* __restrict__ v,
    unsigned short* __restrict__ qc, unsigned short* __restrict__ kc,
    float* __restrict__ vsum, float* __restrict__ nd, float* __restrict__ out0) {
  const int bid = blockIdx.x;
  const int t = threadIdx.x;
  if (bid == 0 && t == 0) out0[0] = 0.f;
  const float sc = 0.0883883476483184f * 1.4426950408889634f;

  // q: 8 float4-steps, lane-contiguous.
  #pragma unroll
  for (int g = 0; g < 8; ++g) {
    const size_t i4 = (size_t)g * (PG * 256) + (size_t)bid * 256 + t;
    const f32x4v a = __builtin_nontemporal_load(
        reinterpret_cast<const f32x4v*>(qf) + i4);
    u16x4 o;
    o[0] = f2bf(a[0] * sc); o[1] = f2bf(a[1] * sc);
    o[2] = f2bf(a[2] * sc); o[3] = f2bf(a[3] * sc);
    *(reinterpret_cast<u16x4*>(qc) + i4) = o;
  }
  // k: 8 float4-steps.
  #pragma unroll
  for (int g = 0; g < 8; ++g) {
    const size_t i4 = (size_t)g * (PG * 256) + (size_t)bid * 256 + t;
    const f32x4v a = __builtin_nontemporal_load(
        reinterpret_cast<const f32x4v*>(kf) + i4);
    u16x4 o;
    o[0] = f2bf(a[0]); o[1] = f2bf(a[1]);
    o[2] = f2bf(a[2]); o[3] = f2bf(a[3]);
    *(reinterpret_cast<u16x4*>(kc) + i4) = o;
  }

  // vsum: 2 panels/block, lane-contiguous (1KB/instr); 32-lane shfl groups.
  const int w = t >> 6, l = t & 63;
  #pragma unroll
  for (int g = 0; g < (B_ * S_) / PG; ++g) {
    const int u = bid + g * PG;
    const int b = u / S_, s = u % S_;
    const f32x4v* panel =
        reinterpret_cast<const f32x4v*>(v + (((size_t)b * S_ + s) * H_) * D_);
    #pragma unroll
    for (int j = 0; j < 4; ++j) {
      const f32x4v a = __builtin_nontemporal_load(panel + j * 256 + t);
      float sum = a[0] + a[1] + a[2] + a[3];
      sum += __shfl_xor(sum, 1);
      sum += __shfl_xor(sum, 2);
      sum += __shfl_xor(sum, 4);
      sum += __shfl_xor(sum, 8);
      sum += __shfl_xor(sum, 16);
      const int h = j * 8 + w * 2 + (l >> 5);   // row of this 32-lane group
      if ((l & 31) == 0) vsum[((size_t)b * H_ + h) * S_ + s] = sum;
    }
  }

  if (bid < 256) {
    float4* p = reinterpret_cast<float4*>(nd);
    p[(size_t)bid * 256 + t] = float4{0.f, 0.f, 0.f, 0.f};
  }
}

// Main (R15-identical, measured ~32us): block = (bh, qt 128 q-rows, uniform
// k-chunk). 32-row k-subtiles in ring-4 LDS slots (33KB -> 4 blocks/CU),
// depth-2 prefetch, counted vmcnt(3) + raw s_barrier. K DMA = 256B strips at
// 8KB stride (8 x 128B lines/instr, zero inflation) from same-layout bf16;
// XOR-involution swizzle (pre-swizzled global source, linear LDS dest).
__global__ __launch_bounds__(256, 4) void attn_sum(
    const unsigned short* __restrict__ qc, const unsigned short* __restrict__ kc,
    const float* __restrict__ vsum, float* __restrict__ numb,
    float* __restrict__ denb) {
  __shared__ uint4 kbuf[4][512];       // 4 x 8KB
  __shared__ float vsbuf[4][64];       // 4 x 256B

  const int id = blockIdx.x;
  const int y  = id >> 3;
  const int bh = (id & 7) + 8 * (y / CPB);
  const int c  = y % CPB;

  int qt, h, nch;
  if (c < 4)       { qt = c;                 h = 0;            nch = 1; }
  else if (c < 12) { qt = 4 + ((c - 4) >> 1);  h = (c - 4) & 1;  nch = 2; }
  else if (c < 24) { qt = 8 + (c - 12) / 3;    h = (c - 12) % 3; nch = 3; }
  else             { qt = 12 + ((c - 24) >> 2); h = (c - 24) & 3; nch = 4; }
  const int nkt  = 2 * qt + 2;
  const int bas_ = nkt / nch, rem = nkt % nch;
  const int kt0  = h * bas_ + (h < rem ? h : rem);
  const int kt1  = kt0 + bas_ + (h < rem ? 1 : 0);
  const int st0  = 2 * kt0, st1 = 2 * kt1;   // 32-row subtiles

  const int t  = threadIdx.x;
  const int w  = t >> 6;
  const int l  = t & 63;
  const int ln = l & 31, l5 = l >> 5;

  const int b0 = bh >> 5, h0 = bh & 31;
  const int qrow0 = qt * 128 + w * 32;
  const unsigned short* kc0 = kc + ((size_t)b0 * S_ * H_ + h0) * D_;
  const float* vsrc0 = vsum + (size_t)bh * S_;

  // Q A-frags from bf16 [B,S,H,D]: lane-scattered 16B loads, once per block.
  bf16x8 qfrag[8];
  {
    const unsigned short* qp =
        qc + (((size_t)b0 * S_ + qrow0 + ln) * H_ + h0) * D_ + l5 * 8;
    #pragma unroll
    for (int kb8 = 0; kb8 < 8; ++kb8)
      qfrag[kb8] = *reinterpret_cast<const bf16x8*>(qp + kb8 * 16);
  }

  // Stage one 32-row subtile: per wave 2 K-DMAs + 1 vsum-DMA = 3 vmcnt ops.
  auto stage = [&](int st, int slot) {
    #pragma unroll
    for (int j = 0; j < 2; ++j) {
      const int idx = (w * 2 + j) * 64 + l;   // physical 16B slot in subtile
      const int r   = idx >> 4;
      const int p   = idx & 15;
      const int cc  = p ^ (r & 15);           // logical chunk stored here
      const unsigned short* src = kc0 + (size_t)(st * 32 + r) * (H_ * D_) + cc * 8;
      __builtin_amdgcn_global_load_lds(
          (const AS1 void*)src, (AS3 void*)(&kbuf[slot][idx & ~63]), 16, 0, 0);
    }
    __builtin_amdgcn_global_load_lds(
        (const AS1 void*)(vsrc0 + st * 32 + l), (AS3 void*)(&vsbuf[slot][0]), 4, 0, 0);
  };

  float num[16], den[16];
  #pragma unroll
  for (int r = 0; r < 16; ++r) { num[r] = 0.f; den[r] = 0.f; }

  // Prologue: depth-2.
  stage(st0, st0 & 3);
  stage(st0 + 1, (st0 + 1) & 3);

  const int xr = ln & 15;
  for (int st = st0; st < st1; ++st) {
    // Drain batch st (3 ops), leave batch st+1 (3 ops) in flight.
    if (st + 1 < st1) asm volatile("s_waitcnt vmcnt(3)" ::: "memory");
    else              asm volatile("s_waitcnt vmcnt(0)" ::: "memory");
    __builtin_amdgcn_s_barrier();            // raw: no implicit drain
    if (st + 2 < st1) stage(st + 2, (st + 2) & 3);

    const int kbase = st * 32;
    if (kbase <= qrow0 + 31) {               // wave-uniform causal skip
      const int slot = st & 3;
      const uint4* rowb = &kbuf[slot][ln * 16];
      f32x16 sacc = {0.f,0.f,0.f,0.f,0.f,0.f,0.f,0.f,
                     0.f,0.f,0.f,0.f,0.f,0.f,0.f,0.f};
      __builtin_amdgcn_s_setprio(1);
      #pragma unroll
      for (int kb8 = 0; kb8 < 8; ++kb8) {
        const bf16x8 bf = *reinterpret_cast<const bf16x8*>(&rowb[(kb8 * 2 + l5) ^ xr]);
        sacc = __builtin_amdgcn_mfma_f32_32x32x16_bf16(qfrag[kb8], bf, sacc, 0, 0, 0);
      }
      __builtin_amdgcn_s_setprio(0);
      const float vsv = vsbuf[slot][ln];
      if (kbase + 31 <= qrow0) {
        #pragma unroll
        for (int r = 0; r < 16; ++r) {
          const float e = EXP2F(sacc[r]);
          den[r] += e;
          num[r] = fmaf(e, vsv, num[r]);
        }
      } else {
        const int kgc = kbase + ln;
        #pragma unroll
        for (int r = 0; r < 16; ++r) {
          const int qgr = qrow0 + (r & 3) + 8 * (r >> 2) + 4 * l5;
          const float e = (kgc <= qgr) ? EXP2F(sacc[r]) : 0.f;
          den[r] += e;
          num[r] = fmaf(e, vsv, num[r]);
        }
      }
    }
  }

  // Reduce over the 32 k-cols, then one atomic pair per q-row.
  #pragma unroll
  for (int m = 1; m < 32; m <<= 1) {
    #pragma unroll
    for (int r = 0; r < 16; ++r) {
      num[r] += __shfl_xor(num[r], m);
      den[r] += __shfl_xor(den[r], m);
    }
  }
  if (ln == 0) {
    float* nrow = numb + (size_t)bh * S_;
    float* drow = denb + (size_t)bh * S_;
    #pragma unroll
    for (int r = 0; r < 16; ++r) {
      const int qgr = qrow0 + (r & 3) + 8 * (r >> 2) + 4 * l5;
      atomicAdd(&nrow[qgr], num[r]);
      atomicAdd(&drow[qgr], den[r]);
    }
  }
}

// Finalize: sum(num/den) over all q-rows.
__global__ __launch_bounds__(256) void finalize(
    const float* __restrict__ numb, const float* __restrict__ denb,
    float* __restrict__ out) {
  const int i = blockIdx.x * 256 + threadIdx.x;
  float c = numb[i] / denb[i];
  #pragma unroll
  for (int m = 1; m < 64; m <<= 1) c += __shfl_xor(c, m);
  __shared__ float ps[4];
  if ((threadIdx.x & 63) == 0) ps[threadIdx.x >> 6] = c;
  __syncthreads();
  if (threadIdx.x == 0) atomicAdd(out, ps[0] + ps[1] + ps[2] + ps[3]);
}

extern "C" void kernel_launch(void* const* d_in, const int* in_sizes, int n_in,
                              void* d_out, int out_size, void* d_ws, size_t ws_size,
                              hipStream_t stream) {
  const float* q = (const float*)d_in[0];
  const float* k = (const float*)d_in[1];
  const float* v = (const float*)d_in[2];
  float* out = (float*)d_out;

  unsigned short* qc = (unsigned short*)d_ws;                 // 32 MiB
  unsigned short* kc = qc + (size_t)R_ * D_;                  // 32 MiB
  float* vsum = (float*)(kc + (size_t)R_ * D_);               // 512 KiB
  float* numb = vsum + R_;                                    // 512 KiB
  float* denb = numb + R_;                                    // 512 KiB

  hipLaunchKernelGGL(prep, dim3(PG), dim3(256), 0, stream,
                     q, k, v, qc, kc, vsum, numb, out);
  hipLaunchKernelGGL(attn_sum, dim3(64 * CPB), dim3(256), 0, stream,
                     qc, kc, vsum, numb, denb);
  hipLaunchKernelGGL(finalize, dim3(R_ / 256), dim3(256), 0, stream,
                     numb, denb, out);
}

// Round 17
// 106.868 us; speedup vs baseline: 1.2380x; 1.2380x over previous
//
#include <hip/hip_runtime.h>
#include <hip/hip_bf16.h>
#include <stdint.h>

#define B_ 2
#define S_ 2048
#define H_ 32
#define D_ 128
#define R_ (B_*H_*S_)           // 131072 (b,h,s) rows
#define PG 2048                 // prep grid size
#define CPB 27                  // k-chunks per bh (pair structure, <=6 tiles)

typedef __bf16 bf16x8 __attribute__((ext_vector_type(8)));
typedef float  f32x16 __attribute__((ext_vector_type(16)));

#if __has_builtin(__builtin_amdgcn_exp2f)
#define EXP2F(x) __builtin_amdgcn_exp2f(x)
#else
#define EXP2F(x) exp2f(x)
#endif

#define AS1 __attribute__((address_space(1)))
#define AS3 __attribute__((address_space(3)))

__device__ __forceinline__ unsigned short f2bf(float f) {
  unsigned u = __float_as_uint(f);
  u += 0x7FFFu + ((u >> 16) & 1u);
  return (unsigned short)(u >> 16);
}

// Prep (R15-proven, NO nontemporal -- nt defeated cross-replay L3 warmth in
// R16): q,k [B,S,H,D] fp32 -> SAME-layout bf16 (Q gets scale*log2e folded);
// vsum[b,h,s] = sum_d v; zero num/den and the output scalar.
__global__ __launch_bounds__(256) void prep(
    const float* __restrict__ qf, const float* __restrict__ kf,
    const float* __restrict__ v,
    unsigned short* __restrict__ qc, unsigned short* __restrict__ kc,
    float* __restrict__ vsum, float* __restrict__ nd, float* __restrict__ out0) {
  const int bid = blockIdx.x;
  const int t = threadIdx.x;
  if (bid == 0 && t == 0) out0[0] = 0.f;
  const float sc = 0.0883883476483184f * 1.4426950408889634f;

  #pragma unroll
  for (int g = 0; g < 4; ++g) {                 // q: 4 ushort8-units/thread
    const size_t i = (size_t)g * (PG * 256) + (size_t)bid * 256 + t;
    const float4 a = *reinterpret_cast<const float4*>(qf + i * 8);
    const float4 b = *reinterpret_cast<const float4*>(qf + i * 8 + 4);
    union { unsigned short u[8]; uint4 v4; } o;
    o.u[0] = f2bf(a.x * sc); o.u[1] = f2bf(a.y * sc);
    o.u[2] = f2bf(a.z * sc); o.u[3] = f2bf(a.w * sc);
    o.u[4] = f2bf(b.x * sc); o.u[5] = f2bf(b.y * sc);
    o.u[6] = f2bf(b.z * sc); o.u[7] = f2bf(b.w * sc);
    *reinterpret_cast<uint4*>(qc + i * 8) = o.v4;
  }
  #pragma unroll
  for (int g = 0; g < 4; ++g) {                 // k: 4 ushort8-units/thread
    const size_t i = (size_t)g * (PG * 256) + (size_t)bid * 256 + t;
    const float4 a = *reinterpret_cast<const float4*>(kf + i * 8);
    const float4 b = *reinterpret_cast<const float4*>(kf + i * 8 + 4);
    union { unsigned short u[8]; uint4 v4; } o;
    o.u[0] = f2bf(a.x); o.u[1] = f2bf(a.y);
    o.u[2] = f2bf(a.z); o.u[3] = f2bf(a.w);
    o.u[4] = f2bf(b.x); o.u[5] = f2bf(b.y);
    o.u[6] = f2bf(b.z); o.u[7] = f2bf(b.w);
    *reinterpret_cast<uint4*>(kc + i * 8) = o.v4;
  }

  #pragma unroll
  for (int g = 0; g < (B_ * S_) / PG; ++g) {    // vsum: 2 panels/block
    const int u = bid + g * PG;
    const int b = u / S_, s = u % S_;
    const int h = t >> 3, i = t & 7;
    const float* p = v + (((size_t)b * S_ + s) * H_ + h) * D_ + i * 16;
    const float4 a0 = *reinterpret_cast<const float4*>(p + 0);
    const float4 a1 = *reinterpret_cast<const float4*>(p + 4);
    const float4 a2 = *reinterpret_cast<const float4*>(p + 8);
    const float4 a3 = *reinterpret_cast<const float4*>(p + 12);
    float sum = (a0.x+a0.y+a0.z+a0.w) + (a1.x+a1.y+a1.z+a1.w)
              + (a2.x+a2.y+a2.z+a2.w) + (a3.x+a3.y+a3.z+a3.w);
    sum += __shfl_xor(sum, 1);
    sum += __shfl_xor(sum, 2);
    sum += __shfl_xor(sum, 4);
    if (i == 0) vsum[((size_t)b * H_ + h) * S_ + s] = sum;
  }

  if (bid < 256) {
    float4* p = reinterpret_cast<float4*>(nd);
    p[(size_t)bid * 256 + t] = float4{0.f, 0.f, 0.f, 0.f};
  }
}

// Main: block = (bh, q-tile PAIR {2g, 2g+1}, uniform k-chunk of <=6 64-row
// tiles). Each staged K-subtile feeds BOTH q-tiles: K-frags read from LDS
// once, 16 MFMA per 8 ds_reads; staged-K DMA traffic -47% vs single-tile.
// SWAPPED operand order mfma(K, Q): lane owns one q-COLUMN -> accumulators
// are 2 floats per side (vs 32), reduction is one shfl_xor(32), atomics 8x
// fewer. vsv weights broadcast from vsbuf (4 float4 LDS reads, shared by
// both sides). Pipeline: ring-4 slots, depth-2, counted vmcnt(3) + raw
// s_barrier, XOR-involution DMA staging (R9/R15-proven).
__global__ __launch_bounds__(256, 3) void attn_sum(
    const unsigned short* __restrict__ qc, const unsigned short* __restrict__ kc,
    const float* __restrict__ vsum, float* __restrict__ numb,
    float* __restrict__ denb) {
  __shared__ uint4 kbuf[4][512];       // 4 x 8KB
  __shared__ float vsbuf[4][64];       // 4 x 256B

  const int id = blockIdx.x;
  const int y  = id >> 3;
  const int bh = (id & 7) + 8 * (y / CPB);
  const int c  = y % CPB;

  // pair g has 4g+4 k-tiles -> chunks: 1,2,2,3,4,4,5,6 per g.
  int g, h, nch;
  if (c < 1)       { g = 0; h = c;      nch = 1; }
  else if (c < 3)  { g = 1; h = c - 1;  nch = 2; }
  else if (c < 5)  { g = 2; h = c - 3;  nch = 2; }
  else if (c < 8)  { g = 3; h = c - 5;  nch = 3; }
  else if (c < 12) { g = 4; h = c - 8;  nch = 4; }
  else if (c < 16) { g = 5; h = c - 12; nch = 4; }
  else if (c < 21) { g = 6; h = c - 16; nch = 5; }
  else             { g = 7; h = c - 21; nch = 6; }
  const int nkt  = 4 * g + 4;
  const int bas_ = nkt / nch, rem = nkt % nch;
  const int kt0  = h * bas_ + (h < rem ? h : rem);
  const int kt1  = kt0 + bas_ + (h < rem ? 1 : 0);
  const int st0  = 2 * kt0, st1 = 2 * kt1;   // 32-row subtiles (>=8/block)

  const int t  = threadIdx.x;
  const int w  = t >> 6;
  const int l  = t & 63;
  const int ln = l & 31, l5 = l >> 5;

  const int b0 = bh >> 5, h0 = bh & 31;
  const int qminA = (2 * g) * 128 + w * 32;
  const int qminB = (2 * g + 1) * 128 + w * 32;
  const unsigned short* kc0 = kc + ((size_t)b0 * S_ * H_ + h0) * D_;
  const float* vsrc0 = vsum + (size_t)bh * S_;

  // Q B-frags for both tiles (n = q-col = lane&31, k-chunk = kb8*16+l5*8).
  bf16x8 qfA[8], qfB[8];
  {
    const unsigned short* qpA =
        qc + (((size_t)b0 * S_ + qminA + ln) * H_ + h0) * D_ + l5 * 8;
    const unsigned short* qpB =
        qc + (((size_t)b0 * S_ + qminB + ln) * H_ + h0) * D_ + l5 * 8;
    #pragma unroll
    for (int kb8 = 0; kb8 < 8; ++kb8) {
      qfA[kb8] = *reinterpret_cast<const bf16x8*>(qpA + kb8 * 16);
      qfB[kb8] = *reinterpret_cast<const bf16x8*>(qpB + kb8 * 16);
    }
  }

  // Stage one 32-row subtile: 2 K-DMAs + 1 vsum-DMA = 3 vmcnt ops.
  auto stage = [&](int st, int slot) {
    #pragma unroll
    for (int j = 0; j < 2; ++j) {
      const int idx = (w * 2 + j) * 64 + l;   // physical 16B slot in subtile
      const int r   = idx >> 4;
      const int p   = idx & 15;
      const int cc  = p ^ (r & 15);           // logical chunk stored here
      const unsigned short* src = kc0 + (size_t)(st * 32 + r) * (H_ * D_) + cc * 8;
      __builtin_amdgcn_global_load_lds(
          (const AS1 void*)src, (AS3 void*)(&kbuf[slot][idx & ~63]), 16, 0, 0);
    }
    __builtin_amdgcn_global_load_lds(
        (const AS1 void*)(vsrc0 + st * 32 + l), (AS3 void*)(&vsbuf[slot][0]), 4, 0, 0);
  };

  float npA = 0.f, dpA = 0.f, npB = 0.f, dpB = 0.f;

  // Prologue: depth-2.
  stage(st0, st0 & 3);
  stage(st0 + 1, (st0 + 1) & 3);

  const int xr = ln & 15;
  for (int st = st0; st < st1; ++st) {
    if (st + 1 < st1) asm volatile("s_waitcnt vmcnt(3)" ::: "memory");
    else              asm volatile("s_waitcnt vmcnt(0)" ::: "memory");
    __builtin_amdgcn_s_barrier();            // raw: no implicit drain
    if (st + 2 < st1) stage(st + 2, (st + 2) & 3);

    const int kbase = st * 32;
    if (kbase <= qminB + 31) {               // B active (A-active implies this)
      const int slot = st & 3;
      const uint4* rowb = &kbuf[slot][ln * 16];
      // K A-frags (m = k-row = lane&31), shared by both sides.
      bf16x8 kf[8];
      #pragma unroll
      for (int kb8 = 0; kb8 < 8; ++kb8)
        kf[kb8] = *reinterpret_cast<const bf16x8*>(&rowb[(kb8 * 2 + l5) ^ xr]);
      // vsv weights in C/D order: row(r) = (r&3) + 8*(r>>2) + 4*l5.
      const float4 vs0 = *reinterpret_cast<const float4*>(&vsbuf[slot][ 0 + 4 * l5]);
      const float4 vs1 = *reinterpret_cast<const float4*>(&vsbuf[slot][ 8 + 4 * l5]);
      const float4 vs2 = *reinterpret_cast<const float4*>(&vsbuf[slot][16 + 4 * l5]);
      const float4 vs3 = *reinterpret_cast<const float4*>(&vsbuf[slot][24 + 4 * l5]);
      const float vsa[16] = {vs0.x,vs0.y,vs0.z,vs0.w, vs1.x,vs1.y,vs1.z,vs1.w,
                             vs2.x,vs2.y,vs2.z,vs2.w, vs3.x,vs3.y,vs3.z,vs3.w};

      // ---- side B ----
      {
        f32x16 sacc = {0.f,0.f,0.f,0.f,0.f,0.f,0.f,0.f,
                       0.f,0.f,0.f,0.f,0.f,0.f,0.f,0.f};
        __builtin_amdgcn_s_setprio(1);
        #pragma unroll
        for (int kb8 = 0; kb8 < 8; ++kb8)
          sacc = __builtin_amdgcn_mfma_f32_32x32x16_bf16(kf[kb8], qfB[kb8], sacc, 0, 0, 0);
        __builtin_amdgcn_s_setprio(0);
        if (kbase + 31 <= qminB) {
          #pragma unroll
          for (int r = 0; r < 16; ++r) {
            const float e = EXP2F(sacc[r]);
            dpB += e;
            npB = fmaf(e, vsa[r], npB);
          }
        } else {
          const int qg = qminB + ln;
          #pragma unroll
          for (int r = 0; r < 16; ++r) {
            const int kr = kbase + (r & 3) + 8 * (r >> 2) + 4 * l5;
            const float e = (kr <= qg) ? EXP2F(sacc[r]) : 0.f;
            dpB += e;
            npB = fmaf(e, vsa[r], npB);
          }
        }
      }
      // ---- side A ----
      if (kbase <= qminA + 31) {
        f32x16 sacc = {0.f,0.f,0.f,0.f,0.f,0.f,0.f,0.f,
                       0.f,0.f,0.f,0.f,0.f,0.f,0.f,0.f};
        __builtin_amdgcn_s_setprio(1);
        #pragma unroll
        for (int kb8 = 0; kb8 < 8; ++kb8)
          sacc = __builtin_amdgcn_mfma_f32_32x32x16_bf16(kf[kb8], qfA[kb8], sacc, 0, 0, 0);
        __builtin_amdgcn_s_setprio(0);
        if (kbase + 31 <= qminA) {
          #pragma unroll
          for (int r = 0; r < 16; ++r) {
            const float e = EXP2F(sacc[r]);
            dpA += e;
            npA = fmaf(e, vsa[r], npA);
          }
        } else {
          const int qg = qminA + ln;
          #pragma unroll
          for (int r = 0; r < 16; ++r) {
            const int kr = kbase + (r & 3) + 8 * (r >> 2) + 4 * l5;
            const float e = (kr <= qg) ? EXP2F(sacc[r]) : 0.f;
            dpA += e;
            npA = fmaf(e, vsa[r], npA);
          }
        }
      }
    }
  }

  // Combine l5 halves (same q-col, disjoint k-rows); 2 atomic pairs per col.
  npA += __shfl_xor(npA, 32); dpA += __shfl_xor(dpA, 32);
  npB += __shfl_xor(npB, 32); dpB += __shfl_xor(dpB, 32);
  if (l5 == 0) {
    float* nrow = numb + (size_t)bh * S_;
    float* drow = denb + (size_t)bh * S_;
    atomicAdd(&nrow[qminA + ln], npA);
    atomicAdd(&drow[qminA + ln], dpA);
    atomicAdd(&nrow[qminB + ln], npB);
    atomicAdd(&drow[qminB + ln], dpB);
  }
}

// Finalize: sum(num/den) over all q-rows.
__global__ __launch_bounds__(256) void finalize(
    const float* __restrict__ numb, const float* __restrict__ denb,
    float* __restrict__ out) {
  const int i = blockIdx.x * 256 + threadIdx.x;
  float c = numb[i] / denb[i];
  #pragma unroll
  for (int m = 1; m < 64; m <<= 1) c += __shfl_xor(c, m);
  __shared__ float ps[4];
  if ((threadIdx.x & 63) == 0) ps[threadIdx.x >> 6] = c;
  __syncthreads();
  if (threadIdx.x == 0) atomicAdd(out, ps[0] + ps[1] + ps[2] + ps[3]);
}

extern "C" void kernel_launch(void* const* d_in, const int* in_sizes, int n_in,
                              void* d_out, int out_size, void* d_ws, size_t ws_size,
                              hipStream_t stream) {
  const float* q = (const float*)d_in[0];
  const float* k = (const float*)d_in[1];
  const float* v = (const float*)d_in[2];
  float* out = (float*)d_out;

  unsigned short* qc = (unsigned short*)d_ws;                 // 32 MiB
  unsigned short* kc = qc + (size_t)R_ * D_;                  // 32 MiB
  float* vsum = (float*)(kc + (size_t)R_ * D_);               // 512 KiB
  float* numb = vsum + R_;                                    // 512 KiB
  float* denb = numb + R_;                                    // 512 KiB

  hipLaunchKernelGGL(prep, dim3(PG), dim3(256), 0, stream,
                     q, k, v, qc, kc, vsum, numb, out);
  hipLaunchKernelGGL(attn_sum, dim3(64 * CPB), dim3(256), 0, stream,
                     qc, kc, vsum, numb, denb);
  hipLaunchKernelGGL(finalize, dim3(R_ / 256), dim3(256), 0, stream,
                     numb, denb, out);
}